// Round 4
// baseline (469.769 us; speedup 1.0000x reference)
//
#include <hip/hip_runtime.h>
#include <hip/hip_bf16.h>

// Problem constants (match reference setup_inputs)
#define N_VAR (1 << 22)   // variable nodes
#define DV    4
#define M_CHK (1 << 21)   // check nodes
#define DC    8
#define N_ITER 5
#define E_TOT (N_VAR * DV)

// Native clang vector types: __builtin_nontemporal_load/store requires
// scalar or ext_vector_type pointers (HIP_vector_type structs are invalid).
typedef int   iv4 __attribute__((ext_vector_type(4)));
typedef unsigned uv4 __attribute__((ext_vector_type(4)));
typedef float fv4 __attribute__((ext_vector_type(4)));

// One thread per check node: 8 messages live in registers across all 5
// iterations (non-extrinsic min-sum + permutation scatter => checks are
// fully independent until the final per-variable sum).
// Final messages are bf16 PLAIN-stored to ws[e] — cn_adj is a permutation of
// [0, E), so no two checks write the same slot (no atomics needed).
// Iterations are f32-exact; only the final store is RNE-rounded to bf16.
__global__ __launch_bounds__(256) void nbp_check_kernel(const float* __restrict__ llr0,
                                                        const float* __restrict__ gamma_p,
                                                        const iv4* __restrict__ cn_adj4,
                                                        __hip_bfloat16* __restrict__ ws) {
    const int m = blockIdx.x * blockDim.x + threadIdx.x;
    const float gamma = gamma_p[0];

    // 8 flat edge indices, coalesced 32B load, non-temporal (streamed once;
    // keep L2 capacity for the llr0 gather working set).
    iv4 a0 = __builtin_nontemporal_load(&cn_adj4[(size_t)m * 2]);
    iv4 a1 = __builtin_nontemporal_load(&cn_adj4[(size_t)m * 2 + 1]);
    int e[DC] = {a0.x, a0.y, a0.z, a0.w, a1.x, a1.y, a1.z, a1.w};

    // Gather llr0 of each edge's variable (edge e -> variable e >> 2); cached.
    float l[DC];
    float msg[DC];
#pragma unroll
    for (int d = 0; d < DC; ++d) {
        l[d] = llr0[e[d] >> 2];
    }

    // Iteration 1 peeled: msg==0 -> min|msg|==0 -> c2v = gamma*1*0 = 0 exactly,
    // so msg_new = llr0 + 0 - 0 = llr0.
#pragma unroll
    for (int d = 0; d < DC; ++d) msg[d] = l[d];

#pragma unroll
    for (int it = 1; it < N_ITER; ++it) {
        // sign product with the reference's +1e-12 shift (jnp.sign semantics)
        float s = 1.0f;
        float mn = fabsf(msg[0]);
#pragma unroll
        for (int d = 0; d < DC; ++d) {
            float t = msg[d] + 1e-12f;
            s *= (t > 0.0f) ? 1.0f : ((t < 0.0f) ? -1.0f : 0.0f);
            if (d > 0) mn = fminf(mn, fabsf(msg[d]));
        }
        float c2v = gamma * s * mn;
        // v2c_new = (llr0 + c2v) - v2c  (same association as reference)
#pragma unroll
        for (int d = 0; d < DC; ++d) {
            msg[d] = (l[d] + c2v) - msg[d];
        }
    }

    // Scattered plain 2B stores (no RMW): every edge slot written exactly once.
#pragma unroll
    for (int d = 0; d < DC; ++d) {
        ws[e[d]] = __float2bfloat16(msg[d]);
    }
}

// One thread per 4 variables: coalesced reads of 16 bf16 edge messages (2x16B),
// float4 llr0/out. out[n] = llr0[n] + (((m0+m1)+m2)+m3).
__global__ __launch_bounds__(256) void nbp_var_reduce(const fv4* __restrict__ llr0_4,
                                                      const uv4* __restrict__ ws_u4,
                                                      fv4* __restrict__ out_4) {
    const int t = blockIdx.x * blockDim.x + threadIdx.x;
    uv4 wa = __builtin_nontemporal_load(&ws_u4[(size_t)t * 2]);      // vars 4t, 4t+1
    uv4 wb = __builtin_nontemporal_load(&ws_u4[(size_t)t * 2 + 1]);  // vars 4t+2, 4t+3
    fv4 l = __builtin_nontemporal_load(&llr0_4[t]);

    unsigned u[8] = {wa.x, wa.y, wa.z, wa.w, wb.x, wb.y, wb.z, wb.w};
    float msg[16];
#pragma unroll
    for (int i = 0; i < 8; ++i) {
        // each u32 holds two bf16 messages (little-endian: low half first)
        unsigned lo = (u[i] & 0xFFFFu) << 16;
        unsigned hi = (u[i] & 0xFFFF0000u);
        msg[2 * i]     = __uint_as_float(lo);
        msg[2 * i + 1] = __uint_as_float(hi);
    }

    fv4 o;
    o.x = l.x + (((msg[0]  + msg[1])  + msg[2])  + msg[3]);
    o.y = l.y + (((msg[4]  + msg[5])  + msg[6])  + msg[7]);
    o.z = l.z + (((msg[8]  + msg[9])  + msg[10]) + msg[11]);
    o.w = l.w + (((msg[12] + msg[13]) + msg[14]) + msg[15]);
    __builtin_nontemporal_store(o, &out_4[t]);
}

extern "C" void kernel_launch(void* const* d_in, const int* in_sizes, int n_in,
                              void* d_out, int out_size, void* d_ws, size_t ws_size,
                              hipStream_t stream) {
    const float* llr0   = (const float*)d_in[0];
    const float* gamma  = (const float*)d_in[1];
    // d_in[2] = vn_adj: only its sign is used in the reference; regular code -> no padding, unused.
    const int*   cn_adj = (const int*)d_in[3];
    float* out = (float*)d_out;
    __hip_bfloat16* ws = (__hip_bfloat16*)d_ws;   // E_TOT bf16 = 32 MB per-edge message buffer

    // 1) per-check compute + scattered bf16 per-edge stores
    nbp_check_kernel<<<M_CHK / 256, 256, 0, stream>>>(llr0, gamma, (const iv4*)cn_adj, ws);

    // 2) per-variable coalesced reduce: out = llr0 + sum(ws[4n..4n+3])
    nbp_var_reduce<<<(N_VAR / 4) / 256, 256, 0, stream>>>(
        (const fv4*)llr0, (const uv4*)ws, (fv4*)out);
}